// Round 6
// baseline (1486.292 us; speedup 1.0000x reference)
//
#include <hip/hip_runtime.h>
#include <hip/hip_bf16.h>

// GNN message passing: gather(x[src],x[tgt],ef) -> MLP(112->128->128->48) -> scatter-mean.
// R14 = R11 restructured for OCCUPANCY: all three weight matrices stream from global
// (L2-resident, 76KB total) instead of LDS. LDS drops 146->~68KB -> 2 blocks/CU ->
// 4 waves/SIMD (was 2). R11 was latency-bound at 2 waves/SIMD (no pipe >50% measured);
// doubling TLP attacks exposed ds_read/MFMA/gather latency directly.
// VGPR discipline (R10/R12/R13 lesson: allocator HARD-CAPS at 128 and spills past it,
// regardless of launch_bounds): the gather register prefetch v[14] (56 VGPR live across
// MFMA) is DELETED -- 4-wave TLP replaces it; v[] is now transient inside the convert
// phase. Only srt is prefetched (2 VGPR). Peak ~= bf(32) + w-pingpong(32) + misc < 128.
// Weight L2 demand: 8 waves x 76KB x 6250 tiles = 3.8GB ~= 25 TB/s < 34.5 TB/s ceiling.
// R11 kept: barrier-free tile loop, per-wave run enum (shfl+ballot) + wave-private
// reduce (boundary runs atomicAdd, interior plain store), swizzled ea layout.

#define NN 100000
#define NE 1600000
#define NF 48
#define TOT 112
#define HID 128
#define TILE 256
#define NTILE 6250  // NE/256

typedef __attribute__((ext_vector_type(8))) short short8;
typedef __attribute__((ext_vector_type(4))) float floatx4;

__device__ __forceinline__ unsigned short f2bf(float f) {
    union { float f; unsigned u; } v; v.f = f;
    unsigned u = v.u;
    return (unsigned short)((u + 0x7FFFu + ((u >> 16) & 1u)) >> 16);  // RNE
}
__device__ __forceinline__ unsigned pk2(float a, float b) {
    __hip_bfloat162 h = __float22bfloat162_rn(make_float2(a, b));
    return *(unsigned*)&h;  // low16 = a, high16 = b
}

// ---- hist (blocks 0..6249) + prep W->WT bf16 (blocks 6250..6401)
__global__ void hist_prep_kernel(const int* __restrict__ ei, int* __restrict__ cnt,
                                 const float* __restrict__ W1, const float* __restrict__ W2,
                                 const float* __restrict__ W3,
                                 unsigned short* __restrict__ wt1,
                                 unsigned short* __restrict__ wt2,
                                 unsigned short* __restrict__ wt3) {
    if (blockIdx.x < NTILE) {
        int e = blockIdx.x * 256 + threadIdx.x;  // NE exact
        atomicAdd(cnt + ei[NE + e], 1);
        return;
    }
    int idx = (blockIdx.x - NTILE) * 256 + threadIdx.x;
    if (idx < 16384) {
        int n = idx >> 7, k = idx & 127;
        wt1[idx] = (k < TOT) ? f2bf(W1[k * HID + n]) : (unsigned short)0;
    } else if (idx < 32768) {
        int j = idx - 16384; int n = j >> 7, k = j & 127;
        wt2[j] = f2bf(W2[k * HID + n]);
    } else if (idx < 38912) {
        int j = idx - 32768; int n = j >> 7, k = j & 127;
        wt3[j] = f2bf(W3[k * NF + n]);
    }
}

// pure block scan + one atomic/block -> exclusive offsets
__global__ void scan_kernel(const int* __restrict__ cnt, int* __restrict__ off,
                            int* __restrict__ counter) {
    __shared__ int sd[256];
    __shared__ int sbase;
    int tid = threadIdx.x;
    int n = blockIdx.x * 256 + tid;
    int v = (n < NN) ? cnt[n] : 0;
    sd[tid] = v;
    __syncthreads();
#pragma unroll
    for (int d = 1; d < 256; d <<= 1) {
        int t = (tid >= d) ? sd[tid - d] : 0;
        __syncthreads();
        sd[tid] += t;
        __syncthreads();
    }
    if (tid == 255) sbase = atomicAdd(counter, sd[255]);
    __syncthreads();
    if (n < NN) off[n] = sbase + sd[tid] - v;  // exclusive
}

__global__ void place_kernel(const int* __restrict__ ei, int* __restrict__ off,
                             unsigned long long* __restrict__ srt) {
    int e = blockIdx.x * 256 + threadIdx.x;  // NE exact
    int t = ei[NE + e];
    int p = atomicAdd(off + t, 1);  // off consumed (dead after this kernel)
    srt[p] = (unsigned long long)e | ((unsigned long long)ei[e] << 21) |
             ((unsigned long long)t << 38);
}

// swizzled LDS frag helper: row stride 256B, 16B granules, granule g stored at g^(row&15)
__device__ __forceinline__ const short8* frag_ptr(const unsigned short* base, int row, int s,
                                                  int lane15, int quad) {
    return (const short8*)((const char*)base + row * 256 + (((s * 4 + quad) ^ lane15) << 4));
}

// issue 14 float4 gather loads for half an edge row (sub = which half)
__device__ __forceinline__ void gather_issue(const float* __restrict__ x,
                                             const float* __restrict__ ef,
                                             unsigned long long pk, int sub, float4* v) {
    int eid = (int)(pk & 0x1FFFFFull);
    int src = (int)((pk >> 21) & 0x1FFFFull);
    int tgt = (int)(pk >> 38);
#pragma unroll
    for (int j = 0; j < 14; ++j) {
        int p = 2 * j + sub;
        const float4* gp;
        if (p < 12)      gp = (const float4*)(x + 48 * (size_t)src) + p;
        else if (p < 24) gp = (const float4*)(x + 48 * (size_t)tgt) + (p - 12);
        else             gp = (const float4*)(ef + 16 * (size_t)eid) + (p - 24);
        v[j] = *gp;
    }
}

__launch_bounds__(512, 4)
__global__ void gemm_kernel(const float* __restrict__ x, const float* __restrict__ ef,
                            const unsigned long long* __restrict__ srt,
                            const unsigned short* __restrict__ wt1,
                            const unsigned short* __restrict__ wt2,
                            const unsigned short* __restrict__ wt3,
                            const float* __restrict__ b1, const float* __restrict__ b2,
                            float* __restrict__ out_acc) {
    __shared__ __align__(16) unsigned short ea[TILE * 128];  // 64 KB: E -> h1 -> h2 -> msg
    __shared__ float lb1[128], lb2[128];
    __shared__ int wseg_start[8][33];  // per-wave run starts + sentinel
    __shared__ int wseg_tgt[8][32];

    const int tid = threadIdx.x;
    if (tid < 128) lb1[tid] = b1[tid];
    else if (tid < 256) lb2[tid - 128] = b2[tid - 128];
    __syncthreads();  // biases read-only from here on; no further barriers needed

    const int l15 = tid & 15;
    const int q = (tid & 63) >> 4;
    const int ln = tid & 63;
    const int wave = tid >> 6;
    const int sub = ln & 1;                  // 2 lanes per edge row
    const int grow = wave * 32 + (ln >> 1);  // tile-local edge row (0..255)
    const int gl15 = grow & 15;
    const int G = gridDim.x;

    // per-thread constant bases for streamed weight frags:
    // frag(mt,s) of layer L at wbase + mt*16*128 + s*32 shorts (row mt*16+l15, k s*32+q*8)
    const unsigned short* w1base = wt1 + l15 * 128 + q * 8;
    const unsigned short* w2base = wt2 + l15 * 128 + q * 8;
    const unsigned short* w3base = wt3 + l15 * 128 + q * 8;

    // srt prefetched 1 tile ahead (2 VGPR; the gather itself relies on 4-wave TLP)
    unsigned long long pkCur = srt[(size_t)blockIdx.x * TILE + grow];

    for (int tile = blockIdx.x; tile < NTILE; tile += G) {
        unsigned long long pkNext = (tile + G < NTILE)
            ? srt[(size_t)(tile + G) * TILE + grow] : 0ull;
        // ---- gather + convert + per-wave run enumeration (all wave-private)
        int nrun;
        {
            float4 v[14];                       // transient: dead after this block
            gather_issue(x, ef, pkCur, sub, v); // issue first; enum VALU overlaps latency
            int tgt = (int)(pkCur >> 38);
            int tprev = __shfl(tgt, ln - 2);    // tgt of previous edge row
            int r = ln >> 1;                    // chunk-local row (0..31)
            int startf = (r == 0) || (tgt != tprev);
            unsigned long long mask = __ballot(startf && (sub == 0));
            nrun = __popcll(mask);
            if (startf && sub == 0) {
                int sid = __popcll(mask & ((1ull << ln) - 1ull));
                wseg_start[wave][sid] = r;
                wseg_tgt[wave][sid] = tgt;
            }
            if (ln == 0) wseg_start[wave][nrun] = 32;  // sentinel
#pragma unroll
            for (int j = 0; j < 14; ++j) {
                uint2 h = make_uint2(pk2(v[j].x, v[j].y), pk2(v[j].z, v[j].w));
                *(uint2*)((char*)ea + grow * 256 + ((j ^ gl15) << 4) + (sub << 3)) = h;
            }
            // zero-pad cols 112..127: granules 14,15 (one uint4 per lane)
            *(uint4*)((char*)ea + grow * 256 + (((14 + sub) ^ gl15) << 4)) =
                make_uint4(0u, 0u, 0u, 0u);
        }
        pkCur = pkNext;

        __builtin_amdgcn_s_setprio(1);
        // ---- L1, L2: weights streamed from global (2-deep per-mt ping-pong), h in-place
#pragma unroll
        for (int layer = 0; layer < 2; ++layer) {
            const unsigned short* wb = layer ? w2base : w1base;
            const float* lb = layer ? lb2 : lb1;
            short8 bf[2][4];
#pragma unroll
            for (int gi = 0; gi < 2; ++gi)
#pragma unroll
                for (int s = 0; s < 4; ++s)
                    bf[gi][s] = *frag_ptr(ea, (wave * 2 + gi) * 16 + l15, s, l15, q);
            short8 w[2][4];
#pragma unroll
            for (int s = 0; s < 4; ++s)
                w[0][s] = *(const short8*)(wb + s * 32);
#pragma unroll
            for (int mt = 0; mt < 8; ++mt) {
                if (mt < 7) {
#pragma unroll
                    for (int s = 0; s < 4; ++s)
                        w[(mt + 1) & 1][s] = *(const short8*)(wb + (mt + 1) * 2048 + s * 32);
                }
                floatx4 a0 = (floatx4){0.f, 0.f, 0.f, 0.f};
                floatx4 a1 = (floatx4){0.f, 0.f, 0.f, 0.f};
#pragma unroll
                for (int s = 0; s < 4; ++s) {
                    a0 = __builtin_amdgcn_mfma_f32_16x16x32_bf16(w[mt & 1][s], bf[0][s], a0, 0, 0, 0);
                    a1 = __builtin_amdgcn_mfma_f32_16x16x32_bf16(w[mt & 1][s], bf[1][s], a1, 0, 0, 0);
                }
                int f0 = mt * 16 + q * 4;
                const float4 bv = *(const float4*)(lb + f0);
                uint2 h0 = make_uint2(pk2(fmaxf(a0[0] + bv.x, 0.f), fmaxf(a0[1] + bv.y, 0.f)),
                                      pk2(fmaxf(a0[2] + bv.z, 0.f), fmaxf(a0[3] + bv.w, 0.f)));
                uint2 h1 = make_uint2(pk2(fmaxf(a1[0] + bv.x, 0.f), fmaxf(a1[1] + bv.y, 0.f)),
                                      pk2(fmaxf(a1[2] + bv.z, 0.f), fmaxf(a1[3] + bv.w, 0.f)));
                int gran = 2 * mt + (q >> 1), off8 = (q & 1) << 3;
                *(uint2*)((char*)ea + (wave * 32 + l15) * 256 + ((gran ^ l15) << 4) + off8) = h0;
                *(uint2*)((char*)ea + (wave * 32 + 16 + l15) * 256 + ((gran ^ l15) << 4) + off8) = h1;
            }
        }
        // ---- L3: streamed weights, msg fp32 in-place (h2 dead after frag reads)
        {
            short8 bf[2][4];
#pragma unroll
            for (int gi = 0; gi < 2; ++gi)
#pragma unroll
                for (int s = 0; s < 4; ++s)
                    bf[gi][s] = *frag_ptr(ea, (wave * 2 + gi) * 16 + l15, s, l15, q);
            short8 w[2][4];
#pragma unroll
            for (int s = 0; s < 4; ++s)
                w[0][s] = *(const short8*)(w3base + s * 32);
#pragma unroll
            for (int mt = 0; mt < 3; ++mt) {
                if (mt < 2) {
#pragma unroll
                    for (int s = 0; s < 4; ++s)
                        w[(mt + 1) & 1][s] = *(const short8*)(w3base + (mt + 1) * 2048 + s * 32);
                }
                floatx4 a0 = (floatx4){0.f, 0.f, 0.f, 0.f};
                floatx4 a1 = (floatx4){0.f, 0.f, 0.f, 0.f};
#pragma unroll
                for (int s = 0; s < 4; ++s) {
                    a0 = __builtin_amdgcn_mfma_f32_16x16x32_bf16(w[mt & 1][s], bf[0][s], a0, 0, 0, 0);
                    a1 = __builtin_amdgcn_mfma_f32_16x16x32_bf16(w[mt & 1][s], bf[1][s], a1, 0, 0, 0);
                }
                int gran = mt * 4 + q;  // fp32 granule, full 16B
                *(float4*)((char*)ea + (wave * 32 + l15) * 256 + ((gran ^ l15) << 4)) =
                    *(float4*)&a0;
                *(float4*)((char*)ea + (wave * 32 + 16 + l15) * 256 + ((gran ^ l15) << 4)) =
                    *(float4*)&a1;
            }
        }
        __builtin_amdgcn_s_setprio(0);
        // ---- per-wave segment reduce over OWN 32 rows (no barrier: same-wave DS
        //      ordering covers msg writes above and wseg writes at convert).
        //      Boundary runs (k==0 / k==nrun-1) may continue in neighboring chunks or
        //      blocks -> atomicAdd; interior runs are globally exclusive (sorted srt)
        //      -> plain store. out_acc is zero-initialized.
        if (ln < 48) {
            const int gcol = ln >> 2, coff = (ln & 3) << 2;
            const char* wbase = (const char*)ea + wave * 32 * 256;  // wave*32 % 16 == 0
            for (int k = 0; k < nrun; ++k) {
                int a = wseg_start[wave][k], bnd = wseg_start[wave][k + 1];
                float s0 = 0.f, s1f = 0.f;
                int p = a;
                for (; p + 1 < bnd; p += 2) {
                    s0  += *(const float*)(wbase + p * 256 + ((gcol ^ (p & 15)) << 4) + coff);
                    s1f += *(const float*)(wbase + (p + 1) * 256 +
                                           ((gcol ^ ((p + 1) & 15)) << 4) + coff);
                }
                if (p < bnd)
                    s0 += *(const float*)(wbase + p * 256 + ((gcol ^ (p & 15)) << 4) + coff);
                float sum = s0 + s1f;
                float* dst = out_acc + 48 * (size_t)wseg_tgt[wave][k] + ln;
                if (k == 0 || k == nrun - 1) atomicAdd(dst, sum);  // may span chunk edge
                else *dst = sum;                                   // exclusive run
            }
        }
        // no barrier: each wave proceeds to its next tile independently
    }
}

__global__ void finalize_kernel(const float* __restrict__ x, const int* __restrict__ cnt,
                                const float* __restrict__ b3, float* __restrict__ out) {
    int i = blockIdx.x * 256 + threadIdx.x;  // over NN*12 float4s
    if (i >= NN * 12) return;
    int node = i / 12, j = i % 12;
    float c = (float)cnt[node];
    float4 xv = ((const float4*)x)[i];
    float4 ov = ((const float4*)out)[i];
    float4 bv = ((const float4*)b3)[j];
    float4 r;
    if (c > 0.f) {
        float rc = 1.f / c;
        r.x = xv.x + ov.x * rc + bv.x;
        r.y = xv.y + ov.y * rc + bv.y;
        r.z = xv.z + ov.z * rc + bv.z;
        r.w = xv.w + ov.w * rc + bv.w;
    } else {
        r = xv;
    }
    ((float4*)out)[i] = r;
}

extern "C" void kernel_launch(void* const* d_in, const int* in_sizes, int n_in,
                              void* d_out, int out_size, void* d_ws, size_t ws_size,
                              hipStream_t stream) {
    const float* x  = (const float*)d_in[0];
    const int*   ei = (const int*)d_in[1];
    const float* ef = (const float*)d_in[2];
    const float* W1 = (const float*)d_in[3];
    const float* b1 = (const float*)d_in[4];
    const float* W2 = (const float*)d_in[5];
    const float* b2 = (const float*)d_in[6];
    const float* W3 = (const float*)d_in[7];
    const float* b3 = (const float*)d_in[8];
    float* out = (float*)d_out;

    char* ws = (char*)d_ws;
    int* cnt     = (int*)ws;                    // 400000 B
    int* counter = (int*)(ws + 400000);         // 4 B (zeroed together with cnt)
    int* off     = (int*)(ws + 409600);         // 400000 B
    unsigned short* wt1 = (unsigned short*)(ws + 819456);
    unsigned short* wt2 = wt1 + 16384;
    unsigned short* wt3 = wt2 + 16384;          // ends ~897 KB
    unsigned long long* srt = (unsigned long long*)(ws + 901120);  // 12.8 MB

    hipMemsetAsync(out, 0, (size_t)out_size * sizeof(float), stream);
    hipMemsetAsync(cnt, 0, (size_t)NN * sizeof(int) + 4, stream);
    hist_prep_kernel<<<NTILE + 152, 256, 0, stream>>>(ei, cnt, W1, W2, W3, wt1, wt2, wt3);
    scan_kernel<<<391, 256, 0, stream>>>(cnt, off, counter);
    place_kernel<<<6250, 256, 0, stream>>>(ei, off, srt);
    gemm_kernel<<<512, 512, 0, stream>>>(x, ef, srt, wt1, wt2, wt3, b1, b2, out);
    finalize_kernel<<<4688, 256, 0, stream>>>(x, cnt, b3, out);
}

// Round 7
// 956.464 us; speedup vs baseline: 1.5539x; 1.5539x over previous
//
#include <hip/hip_runtime.h>
#include <hip/hip_bf16.h>

// GNN message passing: gather(x[src],x[tgt],ef) -> MLP(112->128->128->48) -> scatter-mean.
// R15 = R14 with __launch_bounds__(512, 2) -- the single change.
// R14 post-mortem: occupancy play WORKED (46.8%, 2 blocks/CU at 69KB LDS) but
// launch_bounds(512,4) imposed a 64-VGPR/wave cap; the allocator spilled v[14]/w/acc
// to scratch (FETCH 285MB->2.4GB, dur 1127us). VGPR-cap ledger across rounds:
// (512,2)->128 cap [R9/R11 clean at 100], (512,1)->128 [R13], (512,4)->64 [R14].
// This kernel's phase-peak is ~90-100 VGPR (convert: v[14]+misc~80; L1/L2: bf32+w32+
// acc8+addr~86; never simultaneous) -> fits the 128 cap; HW grants 2 blocks/CU since
// LDS 69KB<=80KB and VGPR<=128.
// Structure kept from R14: all weights streamed from global (L2-resident 76KB, ~25TB/s
// demand < 34.5 ceiling), no gather register prefetch (4-wave/SIMD TLP hides it),
// srt 1 ahead. R11 kept: barrier-free tile loop, per-wave run enum + wave-private
// reduce (boundary atomicAdd, interior plain store), swizzled ea layout.

#define NN 100000
#define NE 1600000
#define NF 48
#define TOT 112
#define HID 128
#define TILE 256
#define NTILE 6250  // NE/256

typedef __attribute__((ext_vector_type(8))) short short8;
typedef __attribute__((ext_vector_type(4))) float floatx4;

__device__ __forceinline__ unsigned short f2bf(float f) {
    union { float f; unsigned u; } v; v.f = f;
    unsigned u = v.u;
    return (unsigned short)((u + 0x7FFFu + ((u >> 16) & 1u)) >> 16);  // RNE
}
__device__ __forceinline__ unsigned pk2(float a, float b) {
    __hip_bfloat162 h = __float22bfloat162_rn(make_float2(a, b));
    return *(unsigned*)&h;  // low16 = a, high16 = b
}

// ---- hist (blocks 0..6249) + prep W->WT bf16 (blocks 6250..6401)
__global__ void hist_prep_kernel(const int* __restrict__ ei, int* __restrict__ cnt,
                                 const float* __restrict__ W1, const float* __restrict__ W2,
                                 const float* __restrict__ W3,
                                 unsigned short* __restrict__ wt1,
                                 unsigned short* __restrict__ wt2,
                                 unsigned short* __restrict__ wt3) {
    if (blockIdx.x < NTILE) {
        int e = blockIdx.x * 256 + threadIdx.x;  // NE exact
        atomicAdd(cnt + ei[NE + e], 1);
        return;
    }
    int idx = (blockIdx.x - NTILE) * 256 + threadIdx.x;
    if (idx < 16384) {
        int n = idx >> 7, k = idx & 127;
        wt1[idx] = (k < TOT) ? f2bf(W1[k * HID + n]) : (unsigned short)0;
    } else if (idx < 32768) {
        int j = idx - 16384; int n = j >> 7, k = j & 127;
        wt2[j] = f2bf(W2[k * HID + n]);
    } else if (idx < 38912) {
        int j = idx - 32768; int n = j >> 7, k = j & 127;
        wt3[j] = f2bf(W3[k * NF + n]);
    }
}

// pure block scan + one atomic/block -> exclusive offsets
__global__ void scan_kernel(const int* __restrict__ cnt, int* __restrict__ off,
                            int* __restrict__ counter) {
    __shared__ int sd[256];
    __shared__ int sbase;
    int tid = threadIdx.x;
    int n = blockIdx.x * 256 + tid;
    int v = (n < NN) ? cnt[n] : 0;
    sd[tid] = v;
    __syncthreads();
#pragma unroll
    for (int d = 1; d < 256; d <<= 1) {
        int t = (tid >= d) ? sd[tid - d] : 0;
        __syncthreads();
        sd[tid] += t;
        __syncthreads();
    }
    if (tid == 255) sbase = atomicAdd(counter, sd[255]);
    __syncthreads();
    if (n < NN) off[n] = sbase + sd[tid] - v;  // exclusive
}

__global__ void place_kernel(const int* __restrict__ ei, int* __restrict__ off,
                             unsigned long long* __restrict__ srt) {
    int e = blockIdx.x * 256 + threadIdx.x;  // NE exact
    int t = ei[NE + e];
    int p = atomicAdd(off + t, 1);  // off consumed (dead after this kernel)
    srt[p] = (unsigned long long)e | ((unsigned long long)ei[e] << 21) |
             ((unsigned long long)t << 38);
}

// swizzled LDS frag helper: row stride 256B, 16B granules, granule g stored at g^(row&15)
__device__ __forceinline__ const short8* frag_ptr(const unsigned short* base, int row, int s,
                                                  int lane15, int quad) {
    return (const short8*)((const char*)base + row * 256 + (((s * 4 + quad) ^ lane15) << 4));
}

// issue 14 float4 gather loads for half an edge row (sub = which half)
__device__ __forceinline__ void gather_issue(const float* __restrict__ x,
                                             const float* __restrict__ ef,
                                             unsigned long long pk, int sub, float4* v) {
    int eid = (int)(pk & 0x1FFFFFull);
    int src = (int)((pk >> 21) & 0x1FFFFull);
    int tgt = (int)(pk >> 38);
#pragma unroll
    for (int j = 0; j < 14; ++j) {
        int p = 2 * j + sub;
        const float4* gp;
        if (p < 12)      gp = (const float4*)(x + 48 * (size_t)src) + p;
        else if (p < 24) gp = (const float4*)(x + 48 * (size_t)tgt) + (p - 12);
        else             gp = (const float4*)(ef + 16 * (size_t)eid) + (p - 24);
        v[j] = *gp;
    }
}

__launch_bounds__(512, 2)
__global__ void gemm_kernel(const float* __restrict__ x, const float* __restrict__ ef,
                            const unsigned long long* __restrict__ srt,
                            const unsigned short* __restrict__ wt1,
                            const unsigned short* __restrict__ wt2,
                            const unsigned short* __restrict__ wt3,
                            const float* __restrict__ b1, const float* __restrict__ b2,
                            float* __restrict__ out_acc) {
    __shared__ __align__(16) unsigned short ea[TILE * 128];  // 64 KB: E -> h1 -> h2 -> msg
    __shared__ float lb1[128], lb2[128];
    __shared__ int wseg_start[8][33];  // per-wave run starts + sentinel
    __shared__ int wseg_tgt[8][32];

    const int tid = threadIdx.x;
    if (tid < 128) lb1[tid] = b1[tid];
    else if (tid < 256) lb2[tid - 128] = b2[tid - 128];
    __syncthreads();  // biases read-only from here on; no further barriers needed

    const int l15 = tid & 15;
    const int q = (tid & 63) >> 4;
    const int ln = tid & 63;
    const int wave = tid >> 6;
    const int sub = ln & 1;                  // 2 lanes per edge row
    const int grow = wave * 32 + (ln >> 1);  // tile-local edge row (0..255)
    const int gl15 = grow & 15;
    const int G = gridDim.x;

    // per-thread constant bases for streamed weight frags:
    // frag(mt,s) of layer L at wbase + mt*16*128 + s*32 shorts (row mt*16+l15, k s*32+q*8)
    const unsigned short* w1base = wt1 + l15 * 128 + q * 8;
    const unsigned short* w2base = wt2 + l15 * 128 + q * 8;
    const unsigned short* w3base = wt3 + l15 * 128 + q * 8;

    // srt prefetched 1 tile ahead (2 VGPR; the gather itself relies on 4-wave TLP)
    unsigned long long pkCur = srt[(size_t)blockIdx.x * TILE + grow];

    for (int tile = blockIdx.x; tile < NTILE; tile += G) {
        unsigned long long pkNext = (tile + G < NTILE)
            ? srt[(size_t)(tile + G) * TILE + grow] : 0ull;
        // ---- gather + convert + per-wave run enumeration (all wave-private)
        int nrun;
        {
            float4 v[14];                       // transient: dead after this block
            gather_issue(x, ef, pkCur, sub, v); // issue first; enum VALU overlaps latency
            int tgt = (int)(pkCur >> 38);
            int tprev = __shfl(tgt, ln - 2);    // tgt of previous edge row
            int r = ln >> 1;                    // chunk-local row (0..31)
            int startf = (r == 0) || (tgt != tprev);
            unsigned long long mask = __ballot(startf && (sub == 0));
            nrun = __popcll(mask);
            if (startf && sub == 0) {
                int sid = __popcll(mask & ((1ull << ln) - 1ull));
                wseg_start[wave][sid] = r;
                wseg_tgt[wave][sid] = tgt;
            }
            if (ln == 0) wseg_start[wave][nrun] = 32;  // sentinel
#pragma unroll
            for (int j = 0; j < 14; ++j) {
                uint2 h = make_uint2(pk2(v[j].x, v[j].y), pk2(v[j].z, v[j].w));
                *(uint2*)((char*)ea + grow * 256 + ((j ^ gl15) << 4) + (sub << 3)) = h;
            }
            // zero-pad cols 112..127: granules 14,15 (one uint4 per lane)
            *(uint4*)((char*)ea + grow * 256 + (((14 + sub) ^ gl15) << 4)) =
                make_uint4(0u, 0u, 0u, 0u);
        }
        pkCur = pkNext;

        __builtin_amdgcn_s_setprio(1);
        // ---- L1, L2: weights streamed from global (2-deep per-mt ping-pong), h in-place
#pragma unroll
        for (int layer = 0; layer < 2; ++layer) {
            const unsigned short* wb = layer ? w2base : w1base;
            const float* lb = layer ? lb2 : lb1;
            short8 bf[2][4];
#pragma unroll
            for (int gi = 0; gi < 2; ++gi)
#pragma unroll
                for (int s = 0; s < 4; ++s)
                    bf[gi][s] = *frag_ptr(ea, (wave * 2 + gi) * 16 + l15, s, l15, q);
            short8 w[2][4];
#pragma unroll
            for (int s = 0; s < 4; ++s)
                w[0][s] = *(const short8*)(wb + s * 32);
#pragma unroll
            for (int mt = 0; mt < 8; ++mt) {
                if (mt < 7) {
#pragma unroll
                    for (int s = 0; s < 4; ++s)
                        w[(mt + 1) & 1][s] = *(const short8*)(wb + (mt + 1) * 2048 + s * 32);
                }
                floatx4 a0 = (floatx4){0.f, 0.f, 0.f, 0.f};
                floatx4 a1 = (floatx4){0.f, 0.f, 0.f, 0.f};
#pragma unroll
                for (int s = 0; s < 4; ++s) {
                    a0 = __builtin_amdgcn_mfma_f32_16x16x32_bf16(w[mt & 1][s], bf[0][s], a0, 0, 0, 0);
                    a1 = __builtin_amdgcn_mfma_f32_16x16x32_bf16(w[mt & 1][s], bf[1][s], a1, 0, 0, 0);
                }
                int f0 = mt * 16 + q * 4;
                const float4 bv = *(const float4*)(lb + f0);
                uint2 h0 = make_uint2(pk2(fmaxf(a0[0] + bv.x, 0.f), fmaxf(a0[1] + bv.y, 0.f)),
                                      pk2(fmaxf(a0[2] + bv.z, 0.f), fmaxf(a0[3] + bv.w, 0.f)));
                uint2 h1 = make_uint2(pk2(fmaxf(a1[0] + bv.x, 0.f), fmaxf(a1[1] + bv.y, 0.f)),
                                      pk2(fmaxf(a1[2] + bv.z, 0.f), fmaxf(a1[3] + bv.w, 0.f)));
                int gran = 2 * mt + (q >> 1), off8 = (q & 1) << 3;
                *(uint2*)((char*)ea + (wave * 32 + l15) * 256 + ((gran ^ l15) << 4) + off8) = h0;
                *(uint2*)((char*)ea + (wave * 32 + 16 + l15) * 256 + ((gran ^ l15) << 4) + off8) = h1;
            }
        }
        // ---- L3: streamed weights, msg fp32 in-place (h2 dead after frag reads)
        {
            short8 bf[2][4];
#pragma unroll
            for (int gi = 0; gi < 2; ++gi)
#pragma unroll
                for (int s = 0; s < 4; ++s)
                    bf[gi][s] = *frag_ptr(ea, (wave * 2 + gi) * 16 + l15, s, l15, q);
            short8 w[2][4];
#pragma unroll
            for (int s = 0; s < 4; ++s)
                w[0][s] = *(const short8*)(w3base + s * 32);
#pragma unroll
            for (int mt = 0; mt < 3; ++mt) {
                if (mt < 2) {
#pragma unroll
                    for (int s = 0; s < 4; ++s)
                        w[(mt + 1) & 1][s] = *(const short8*)(w3base + (mt + 1) * 2048 + s * 32);
                }
                floatx4 a0 = (floatx4){0.f, 0.f, 0.f, 0.f};
                floatx4 a1 = (floatx4){0.f, 0.f, 0.f, 0.f};
#pragma unroll
                for (int s = 0; s < 4; ++s) {
                    a0 = __builtin_amdgcn_mfma_f32_16x16x32_bf16(w[mt & 1][s], bf[0][s], a0, 0, 0, 0);
                    a1 = __builtin_amdgcn_mfma_f32_16x16x32_bf16(w[mt & 1][s], bf[1][s], a1, 0, 0, 0);
                }
                int gran = mt * 4 + q;  // fp32 granule, full 16B
                *(float4*)((char*)ea + (wave * 32 + l15) * 256 + ((gran ^ l15) << 4)) =
                    *(float4*)&a0;
                *(float4*)((char*)ea + (wave * 32 + 16 + l15) * 256 + ((gran ^ l15) << 4)) =
                    *(float4*)&a1;
            }
        }
        __builtin_amdgcn_s_setprio(0);
        // ---- per-wave segment reduce over OWN 32 rows (no barrier: same-wave DS
        //      ordering covers msg writes above and wseg writes at convert).
        //      Boundary runs (k==0 / k==nrun-1) may continue in neighboring chunks or
        //      blocks -> atomicAdd; interior runs are globally exclusive (sorted srt)
        //      -> plain store. out_acc is zero-initialized.
        if (ln < 48) {
            const int gcol = ln >> 2, coff = (ln & 3) << 2;
            const char* wbase = (const char*)ea + wave * 32 * 256;  // wave*32 % 16 == 0
            for (int k = 0; k < nrun; ++k) {
                int a = wseg_start[wave][k], bnd = wseg_start[wave][k + 1];
                float s0 = 0.f, s1f = 0.f;
                int p = a;
                for (; p + 1 < bnd; p += 2) {
                    s0  += *(const float*)(wbase + p * 256 + ((gcol ^ (p & 15)) << 4) + coff);
                    s1f += *(const float*)(wbase + (p + 1) * 256 +
                                           ((gcol ^ ((p + 1) & 15)) << 4) + coff);
                }
                if (p < bnd)
                    s0 += *(const float*)(wbase + p * 256 + ((gcol ^ (p & 15)) << 4) + coff);
                float sum = s0 + s1f;
                float* dst = out_acc + 48 * (size_t)wseg_tgt[wave][k] + ln;
                if (k == 0 || k == nrun - 1) atomicAdd(dst, sum);  // may span chunk edge
                else *dst = sum;                                   // exclusive run
            }
        }
        // no barrier: each wave proceeds to its next tile independently
    }
}

__global__ void finalize_kernel(const float* __restrict__ x, const int* __restrict__ cnt,
                                const float* __restrict__ b3, float* __restrict__ out) {
    int i = blockIdx.x * 256 + threadIdx.x;  // over NN*12 float4s
    if (i >= NN * 12) return;
    int node = i / 12, j = i % 12;
    float c = (float)cnt[node];
    float4 xv = ((const float4*)x)[i];
    float4 ov = ((const float4*)out)[i];
    float4 bv = ((const float4*)b3)[j];
    float4 r;
    if (c > 0.f) {
        float rc = 1.f / c;
        r.x = xv.x + ov.x * rc + bv.x;
        r.y = xv.y + ov.y * rc + bv.y;
        r.z = xv.z + ov.z * rc + bv.z;
        r.w = xv.w + ov.w * rc + bv.w;
    } else {
        r = xv;
    }
    ((float4*)out)[i] = r;
}

extern "C" void kernel_launch(void* const* d_in, const int* in_sizes, int n_in,
                              void* d_out, int out_size, void* d_ws, size_t ws_size,
                              hipStream_t stream) {
    const float* x  = (const float*)d_in[0];
    const int*   ei = (const int*)d_in[1];
    const float* ef = (const float*)d_in[2];
    const float* W1 = (const float*)d_in[3];
    const float* b1 = (const float*)d_in[4];
    const float* W2 = (const float*)d_in[5];
    const float* b2 = (const float*)d_in[6];
    const float* W3 = (const float*)d_in[7];
    const float* b3 = (const float*)d_in[8];
    float* out = (float*)d_out;

    char* ws = (char*)d_ws;
    int* cnt     = (int*)ws;                    // 400000 B
    int* counter = (int*)(ws + 400000);         // 4 B (zeroed together with cnt)
    int* off     = (int*)(ws + 409600);         // 400000 B
    unsigned short* wt1 = (unsigned short*)(ws + 819456);
    unsigned short* wt2 = wt1 + 16384;
    unsigned short* wt3 = wt2 + 16384;          // ends ~897 KB
    unsigned long long* srt = (unsigned long long*)(ws + 901120);  // 12.8 MB

    hipMemsetAsync(out, 0, (size_t)out_size * sizeof(float), stream);
    hipMemsetAsync(cnt, 0, (size_t)NN * sizeof(int) + 4, stream);
    hist_prep_kernel<<<NTILE + 152, 256, 0, stream>>>(ei, cnt, W1, W2, W3, wt1, wt2, wt3);
    scan_kernel<<<391, 256, 0, stream>>>(cnt, off, counter);
    place_kernel<<<6250, 256, 0, stream>>>(ei, off, srt);
    gemm_kernel<<<512, 512, 0, stream>>>(x, ef, srt, wt1, wt2, wt3, b1, b2, out);
    finalize_kernel<<<4688, 256, 0, stream>>>(x, cnt, b3, out);
}

// Round 8
// 857.477 us; speedup vs baseline: 1.7333x; 1.1154x over previous
//
#include <hip/hip_runtime.h>
#include <hip/hip_bf16.h>

// GNN message passing: gather(x[src],x[tgt],ef) -> MLP(112->128->128->48) -> scatter-mean.
// R16 = 2-blocks/CU occupancy play with FENCED weight streaming.
// R15 post-mortem: spill cause isolated = scheduler HOISTS the unrolled ping-pong's
// global weight loads (32 in flight = 128 VGPR), not declared liveness. Fix here:
// sched_barrier(0) on BOTH sides of each mt iteration -> in-flight loads capped at 8
// by construction (counted-vmcnt pattern). W3 stays in LDS (12KB): total LDS 79.0KB
// <= 80KB -> 2 blocks/CU -> 4 waves/SIMD (R14 proved the occupancy mechanism works).
// The 56-VGPR cross-tile gather prefetch is replaced by in-tile gather in two v[7]
// halves -- 4-wave TLP now hides that latency. Peak liveness ~92 < the 128 cap.
// Pipe budget/tile @2blk: LDS ~5k cyc, MFMA 5.6k, VMEM W1+W2 512KB@56B/cyc ~9k+gather,
// VALU 8.5k -> ~11-14k vs R11's 18.4k.
// R11 kept: barrier-free tile loop, per-wave run enum (shfl+ballot) + wave-private
// reduce (boundary atomicAdd, interior plain store), swizzled ea, setprio around MFMA.
// Spill tripwire: FETCH_SIZE must stay ~285-300MB. If >400MB, streaming is dead.

#define NN 100000
#define NE 1600000
#define NF 48
#define TOT 112
#define HID 128
#define TILE 256
#define NTILE 6250  // NE/256

typedef __attribute__((ext_vector_type(8))) short short8;
typedef __attribute__((ext_vector_type(4))) float floatx4;

__device__ __forceinline__ unsigned short f2bf(float f) {
    union { float f; unsigned u; } v; v.f = f;
    unsigned u = v.u;
    return (unsigned short)((u + 0x7FFFu + ((u >> 16) & 1u)) >> 16);  // RNE
}
__device__ __forceinline__ unsigned pk2(float a, float b) {
    __hip_bfloat162 h = __float22bfloat162_rn(make_float2(a, b));
    return *(unsigned*)&h;  // low16 = a, high16 = b
}

// ---- hist (blocks 0..6249) + prep W->WT bf16 (blocks 6250..6401)
__global__ void hist_prep_kernel(const int* __restrict__ ei, int* __restrict__ cnt,
                                 const float* __restrict__ W1, const float* __restrict__ W2,
                                 const float* __restrict__ W3,
                                 unsigned short* __restrict__ wt1,
                                 unsigned short* __restrict__ wt2,
                                 unsigned short* __restrict__ wt3) {
    if (blockIdx.x < NTILE) {
        int e = blockIdx.x * 256 + threadIdx.x;  // NE exact
        atomicAdd(cnt + ei[NE + e], 1);
        return;
    }
    int idx = (blockIdx.x - NTILE) * 256 + threadIdx.x;
    if (idx < 16384) {
        int n = idx >> 7, k = idx & 127;
        wt1[idx] = (k < TOT) ? f2bf(W1[k * HID + n]) : (unsigned short)0;
    } else if (idx < 32768) {
        int j = idx - 16384; int n = j >> 7, k = j & 127;
        wt2[j] = f2bf(W2[k * HID + n]);
    } else if (idx < 38912) {
        int j = idx - 32768; int n = j >> 7, k = j & 127;
        wt3[j] = f2bf(W3[k * NF + n]);
    }
}

// pure block scan + one atomic/block -> exclusive offsets
__global__ void scan_kernel(const int* __restrict__ cnt, int* __restrict__ off,
                            int* __restrict__ counter) {
    __shared__ int sd[256];
    __shared__ int sbase;
    int tid = threadIdx.x;
    int n = blockIdx.x * 256 + tid;
    int v = (n < NN) ? cnt[n] : 0;
    sd[tid] = v;
    __syncthreads();
#pragma unroll
    for (int d = 1; d < 256; d <<= 1) {
        int t = (tid >= d) ? sd[tid - d] : 0;
        __syncthreads();
        sd[tid] += t;
        __syncthreads();
    }
    if (tid == 255) sbase = atomicAdd(counter, sd[255]);
    __syncthreads();
    if (n < NN) off[n] = sbase + sd[tid] - v;  // exclusive
}

__global__ void place_kernel(const int* __restrict__ ei, int* __restrict__ off,
                             unsigned long long* __restrict__ srt) {
    int e = blockIdx.x * 256 + threadIdx.x;  // NE exact
    int t = ei[NE + e];
    int p = atomicAdd(off + t, 1);  // off consumed (dead after this kernel)
    srt[p] = (unsigned long long)e | ((unsigned long long)ei[e] << 21) |
             ((unsigned long long)t << 38);
}

// swizzled LDS frag helper: row stride 256B, 16B granules, granule g stored at g^(row&15)
__device__ __forceinline__ const short8* frag_ptr(const unsigned short* base, int row, int s,
                                                  int lane15, int quad) {
    return (const short8*)((const char*)base + row * 256 + (((s * 4 + quad) ^ lane15) << 4));
}

// issue 7 float4 gather loads (half h of an edge row; sub = which interleave)
__device__ __forceinline__ void gather_half(const float* __restrict__ x,
                                            const float* __restrict__ ef,
                                            unsigned long long pk, int sub, int h,
                                            float4* v) {
    int eid = (int)(pk & 0x1FFFFFull);
    int src = (int)((pk >> 21) & 0x1FFFFull);
    int tgt = (int)(pk >> 38);
#pragma unroll
    for (int jj = 0; jj < 7; ++jj) {
        int j = h * 7 + jj;
        int p = 2 * j + sub;
        const float4* gp;
        if (p < 12)      gp = (const float4*)(x + 48 * (size_t)src) + p;
        else if (p < 24) gp = (const float4*)(x + 48 * (size_t)tgt) + (p - 12);
        else             gp = (const float4*)(ef + 16 * (size_t)eid) + (p - 24);
        v[jj] = *gp;
    }
}

__launch_bounds__(512, 2)
__global__ void gemm_kernel(const float* __restrict__ x, const float* __restrict__ ef,
                            const unsigned long long* __restrict__ srt,
                            const unsigned short* __restrict__ wt1,
                            const unsigned short* __restrict__ wt2,
                            const unsigned short* __restrict__ wt3,
                            const float* __restrict__ b1, const float* __restrict__ b2,
                            float* __restrict__ out_acc) {
    __shared__ __align__(16) unsigned short ea[TILE * 128];  // 64 KB: E -> h1 -> h2 -> msg
    __shared__ __align__(16) unsigned short lw3[48 * 128];   // 12 KB (stays in LDS)
    __shared__ float lb1[128], lb2[128];
    __shared__ int wseg_start[8][33];  // per-wave run starts + sentinel
    __shared__ int wseg_tgt[8][32];
    // total: 65536 + 12288 + 1024 + 1056 + 1024 = 80928 B <= 81920 (2 blocks/CU)

    const int tid = threadIdx.x;
    // ---- stage L3 weights swizzled (once per persistent block); L1/L2 stream from L2
    const uint4* s3 = (const uint4*)wt3;
    for (int i = tid; i < 768; i += 512) {
        int n = i >> 4, g = i & 15;
        *(uint4*)((char*)lw3 + n * 256 + ((g ^ (n & 15)) << 4)) = s3[i];
    }
    if (tid < 128) lb1[tid] = b1[tid];
    else if (tid < 256) lb2[tid - 128] = b2[tid - 128];
    __syncthreads();  // read-only from here on; no further barriers needed

    const int l15 = tid & 15;
    const int q = (tid & 63) >> 4;
    const int ln = tid & 63;
    const int wave = tid >> 6;
    const int sub = ln & 1;                  // 2 lanes per edge row
    const int grow = wave * 32 + (ln >> 1);  // tile-local edge row (0..255)
    const int gl15 = grow & 15;
    const int G = gridDim.x;

    // per-thread constant bases for streamed weight frags:
    // frag(mt,s) at wbase + mt*2048 + s*32 shorts (row mt*16+l15, k s*32+q*8)
    const unsigned short* w1base = wt1 + l15 * 128 + q * 8;
    const unsigned short* w2base = wt2 + l15 * 128 + q * 8;

    // srt prefetched 1 tile ahead (2 VGPR)
    unsigned long long pkCur = srt[(size_t)blockIdx.x * TILE + grow];

    for (int tile = blockIdx.x; tile < NTILE; tile += G) {
        unsigned long long pkNext = (tile + G < NTILE)
            ? srt[(size_t)(tile + G) * TILE + grow] : 0ull;
        // ---- gather (two v[7] halves; 4-wave TLP hides latency) + convert +
        //      per-wave run enumeration (all wave-private)
        int nrun;
        {
            float4 v0[7];
            gather_half(x, ef, pkCur, sub, 0, v0);  // issue half 0 first
            int tgt = (int)(pkCur >> 38);
            int tprev = __shfl(tgt, ln - 2);    // tgt of previous edge row (enum VALU
            int r = ln >> 1;                    // overlaps the loads' flight)
            int startf = (r == 0) || (tgt != tprev);
            unsigned long long mask = __ballot(startf && (sub == 0));
            nrun = __popcll(mask);
            if (startf && sub == 0) {
                int sid = __popcll(mask & ((1ull << ln) - 1ull));
                wseg_start[wave][sid] = r;
                wseg_tgt[wave][sid] = tgt;
            }
            if (ln == 0) wseg_start[wave][nrun] = 32;  // sentinel
#pragma unroll
            for (int jj = 0; jj < 7; ++jj) {
                uint2 hh = make_uint2(pk2(v0[jj].x, v0[jj].y), pk2(v0[jj].z, v0[jj].w));
                *(uint2*)((char*)ea + grow * 256 + ((jj ^ gl15) << 4) + (sub << 3)) = hh;
            }
            float4 v1[7];
            gather_half(x, ef, pkCur, sub, 1, v1);
#pragma unroll
            for (int jj = 0; jj < 7; ++jj) {
                int j = 7 + jj;
                uint2 hh = make_uint2(pk2(v1[jj].x, v1[jj].y), pk2(v1[jj].z, v1[jj].w));
                *(uint2*)((char*)ea + grow * 256 + ((j ^ gl15) << 4) + (sub << 3)) = hh;
            }
            // zero-pad cols 112..127 (keeps s=3 frag finite; W1 pad rows are zero)
            *(uint4*)((char*)ea + grow * 256 + (((14 + sub) ^ gl15) << 4)) =
                make_uint4(0u, 0u, 0u, 0u);
        }
        pkCur = pkNext;

        __builtin_amdgcn_s_setprio(1);
        // ---- L1, L2: weights streamed from global with FENCED 2-deep ping-pong.
        //      sched_barrier(0) on both sides of each mt body caps in-flight weight
        //      loads at 8 (the R15 spill was the scheduler hoisting all 32).
#pragma unroll
        for (int layer = 0; layer < 2; ++layer) {
            const unsigned short* wb = layer ? w2base : w1base;
            const float* lb = layer ? lb2 : lb1;
            short8 bf[2][4];
#pragma unroll
            for (int gi = 0; gi < 2; ++gi)
#pragma unroll
                for (int s = 0; s < 4; ++s)
                    bf[gi][s] = *frag_ptr(ea, (wave * 2 + gi) * 16 + l15, s, l15, q);
            short8 w[2][4];
#pragma unroll
            for (int s = 0; s < 4; ++s)
                w[0][s] = *(const short8*)(wb + s * 32);
#pragma unroll
            for (int mt = 0; mt < 8; ++mt) {
                if (mt < 7) {
#pragma unroll
                    for (int s = 0; s < 4; ++s)
                        w[(mt + 1) & 1][s] = *(const short8*)(wb + (mt + 1) * 2048 + s * 32);
                }
                __builtin_amdgcn_sched_barrier(0);  // loads stay above, nothing hoists in
                floatx4 a0 = (floatx4){0.f, 0.f, 0.f, 0.f};
                floatx4 a1 = (floatx4){0.f, 0.f, 0.f, 0.f};
#pragma unroll
                for (int s = 0; s < 4; ++s) {
                    a0 = __builtin_amdgcn_mfma_f32_16x16x32_bf16(w[mt & 1][s], bf[0][s], a0, 0, 0, 0);
                    a1 = __builtin_amdgcn_mfma_f32_16x16x32_bf16(w[mt & 1][s], bf[1][s], a1, 0, 0, 0);
                }
                int f0 = mt * 16 + q * 4;
                const float4 bv = *(const float4*)(lb + f0);
                uint2 h0 = make_uint2(pk2(fmaxf(a0[0] + bv.x, 0.f), fmaxf(a0[1] + bv.y, 0.f)),
                                      pk2(fmaxf(a0[2] + bv.z, 0.f), fmaxf(a0[3] + bv.w, 0.f)));
                uint2 h1 = make_uint2(pk2(fmaxf(a1[0] + bv.x, 0.f), fmaxf(a1[1] + bv.y, 0.f)),
                                      pk2(fmaxf(a1[2] + bv.z, 0.f), fmaxf(a1[3] + bv.w, 0.f)));
                int gran = 2 * mt + (q >> 1), off8 = (q & 1) << 3;
                *(uint2*)((char*)ea + (wave * 32 + l15) * 256 + ((gran ^ l15) << 4) + off8) = h0;
                *(uint2*)((char*)ea + (wave * 32 + 16 + l15) * 256 + ((gran ^ l15) << 4) + off8) = h1;
                __builtin_amdgcn_sched_barrier(0);  // next iter's loads can't hoist past
            }
        }
        // ---- L3: weights from LDS (lw3), msg fp32 in-place (h2 dead after frag reads)
        {
            short8 bf[2][4];
#pragma unroll
            for (int gi = 0; gi < 2; ++gi)
#pragma unroll
                for (int s = 0; s < 4; ++s)
                    bf[gi][s] = *frag_ptr(ea, (wave * 2 + gi) * 16 + l15, s, l15, q);
#pragma unroll
            for (int mt = 0; mt < 3; ++mt) {
                floatx4 a0 = (floatx4){0.f, 0.f, 0.f, 0.f};
                floatx4 a1 = (floatx4){0.f, 0.f, 0.f, 0.f};
#pragma unroll
                for (int s = 0; s < 4; ++s) {
                    short8 a = *frag_ptr(lw3, mt * 16 + l15, s, l15, q);
                    a0 = __builtin_amdgcn_mfma_f32_16x16x32_bf16(a, bf[0][s], a0, 0, 0, 0);
                    a1 = __builtin_amdgcn_mfma_f32_16x16x32_bf16(a, bf[1][s], a1, 0, 0, 0);
                }
                int gran = mt * 4 + q;  // fp32 granule, full 16B
                *(float4*)((char*)ea + (wave * 32 + l15) * 256 + ((gran ^ l15) << 4)) =
                    *(float4*)&a0;
                *(float4*)((char*)ea + (wave * 32 + 16 + l15) * 256 + ((gran ^ l15) << 4)) =
                    *(float4*)&a1;
            }
        }
        __builtin_amdgcn_s_setprio(0);
        // ---- per-wave segment reduce over OWN 32 rows (no barrier: same-wave DS
        //      ordering covers msg writes above and wseg writes at convert).
        //      Boundary runs (k==0 / k==nrun-1) may continue in neighboring chunks or
        //      blocks -> atomicAdd; interior runs are globally exclusive (sorted srt)
        //      -> plain store. out_acc is zero-initialized.
        if (ln < 48) {
            const int gcol = ln >> 2, coff = (ln & 3) << 2;
            const char* wbase = (const char*)ea + wave * 32 * 256;  // wave*32 % 16 == 0
            for (int k = 0; k < nrun; ++k) {
                int a = wseg_start[wave][k], bnd = wseg_start[wave][k + 1];
                float s0 = 0.f, s1f = 0.f;
                int p = a;
                for (; p + 1 < bnd; p += 2) {
                    s0  += *(const float*)(wbase + p * 256 + ((gcol ^ (p & 15)) << 4) + coff);
                    s1f += *(const float*)(wbase + (p + 1) * 256 +
                                           ((gcol ^ ((p + 1) & 15)) << 4) + coff);
                }
                if (p < bnd)
                    s0 += *(const float*)(wbase + p * 256 + ((gcol ^ (p & 15)) << 4) + coff);
                float sum = s0 + s1f;
                float* dst = out_acc + 48 * (size_t)wseg_tgt[wave][k] + ln;
                if (k == 0 || k == nrun - 1) atomicAdd(dst, sum);  // may span chunk edge
                else *dst = sum;                                   // exclusive run
            }
        }
        // no barrier: each wave proceeds to its next tile independently
    }
}

__global__ void finalize_kernel(const float* __restrict__ x, const int* __restrict__ cnt,
                                const float* __restrict__ b3, float* __restrict__ out) {
    int i = blockIdx.x * 256 + threadIdx.x;  // over NN*12 float4s
    if (i >= NN * 12) return;
    int node = i / 12, j = i % 12;
    float c = (float)cnt[node];
    float4 xv = ((const float4*)x)[i];
    float4 ov = ((const float4*)out)[i];
    float4 bv = ((const float4*)b3)[j];
    float4 r;
    if (c > 0.f) {
        float rc = 1.f / c;
        r.x = xv.x + ov.x * rc + bv.x;
        r.y = xv.y + ov.y * rc + bv.y;
        r.z = xv.z + ov.z * rc + bv.z;
        r.w = xv.w + ov.w * rc + bv.w;
    } else {
        r = xv;
    }
    ((float4*)out)[i] = r;
}

extern "C" void kernel_launch(void* const* d_in, const int* in_sizes, int n_in,
                              void* d_out, int out_size, void* d_ws, size_t ws_size,
                              hipStream_t stream) {
    const float* x  = (const float*)d_in[0];
    const int*   ei = (const int*)d_in[1];
    const float* ef = (const float*)d_in[2];
    const float* W1 = (const float*)d_in[3];
    const float* b1 = (const float*)d_in[4];
    const float* W2 = (const float*)d_in[5];
    const float* b2 = (const float*)d_in[6];
    const float* W3 = (const float*)d_in[7];
    const float* b3 = (const float*)d_in[8];
    float* out = (float*)d_out;

    char* ws = (char*)d_ws;
    int* cnt     = (int*)ws;                    // 400000 B
    int* counter = (int*)(ws + 400000);         // 4 B (zeroed together with cnt)
    int* off     = (int*)(ws + 409600);         // 400000 B
    unsigned short* wt1 = (unsigned short*)(ws + 819456);
    unsigned short* wt2 = wt1 + 16384;
    unsigned short* wt3 = wt2 + 16384;          // ends ~897 KB
    unsigned long long* srt = (unsigned long long*)(ws + 901120);  // 12.8 MB

    hipMemsetAsync(out, 0, (size_t)out_size * sizeof(float), stream);
    hipMemsetAsync(cnt, 0, (size_t)NN * sizeof(int) + 4, stream);
    hist_prep_kernel<<<NTILE + 152, 256, 0, stream>>>(ei, cnt, W1, W2, W3, wt1, wt2, wt3);
    scan_kernel<<<391, 256, 0, stream>>>(cnt, off, counter);
    place_kernel<<<6250, 256, 0, stream>>>(ei, off, srt);
    gemm_kernel<<<512, 512, 0, stream>>>(x, ef, srt, wt1, wt2, wt3, b1, b2, out);
    finalize_kernel<<<4688, 256, 0, stream>>>(x, cnt, b3, out);
}

// Round 9
// 723.588 us; speedup vs baseline: 2.0541x; 1.1850x over previous
//
#include <hip/hip_runtime.h>
#include <hip/hip_bf16.h>

// GNN message passing: gather(x[src],x[tgt],ef) -> MLP(112->128->128->48) -> scatter-mean.
// R17 = R11 + W1 streamed from global, with sched_barrier(0) WALLS at every phase
// boundary. Spill forensics across R12/R13/R15/R16: the declared working set fits
// (~120 VGPR peak per phase), but the scheduler HOISTS loop-invariant weight loads and
// the gather re-issue across phases, overlapping v[14](56) with w[2][4](32) liveness
// -> >128 -> spill. R16's inner-mt fences halved spill (1.6->1.0GB) but left the L1
// prologue + gather issue free to migrate. Walls between convert | L1 | gather-issue |
// L2/L3 | reduce make cross-phase liveness merging impossible.
// Win mechanism (R12 arithmetic, still valid): -256 LDS b128 weight reads/tile
// (-3.1k cyc off the ~78%-busy LDS pipe) onto the idle VMEM pipe; W1 L2-resident.
// Everything else BYTE-IDENTICAL to R11 (best, 187us gemm): lw2/lw3 in LDS,
// barrier-free tile loop, per-wave run enum + wave-private reduce (boundary atomicAdd,
// interior plain store), cross-tile gather prefetch, setprio around MFMA.
// Tripwire: FETCH_SIZE must stay ~285-300MB. >400MB = hoist won = streaming dead.

#define NN 100000
#define NE 1600000
#define NF 48
#define TOT 112
#define HID 128
#define TILE 256
#define NTILE 6250  // NE/256

typedef __attribute__((ext_vector_type(8))) short short8;
typedef __attribute__((ext_vector_type(4))) float floatx4;

__device__ __forceinline__ unsigned short f2bf(float f) {
    union { float f; unsigned u; } v; v.f = f;
    unsigned u = v.u;
    return (unsigned short)((u + 0x7FFFu + ((u >> 16) & 1u)) >> 16);  // RNE
}
__device__ __forceinline__ unsigned pk2(float a, float b) {
    __hip_bfloat162 h = __float22bfloat162_rn(make_float2(a, b));
    return *(unsigned*)&h;  // low16 = a, high16 = b
}

// ---- hist (blocks 0..6249) + prep W->WT bf16 (blocks 6250..6401)
__global__ void hist_prep_kernel(const int* __restrict__ ei, int* __restrict__ cnt,
                                 const float* __restrict__ W1, const float* __restrict__ W2,
                                 const float* __restrict__ W3,
                                 unsigned short* __restrict__ wt1,
                                 unsigned short* __restrict__ wt2,
                                 unsigned short* __restrict__ wt3) {
    if (blockIdx.x < NTILE) {
        int e = blockIdx.x * 256 + threadIdx.x;  // NE exact
        atomicAdd(cnt + ei[NE + e], 1);
        return;
    }
    int idx = (blockIdx.x - NTILE) * 256 + threadIdx.x;
    if (idx < 16384) {
        int n = idx >> 7, k = idx & 127;
        wt1[idx] = (k < TOT) ? f2bf(W1[k * HID + n]) : (unsigned short)0;
    } else if (idx < 32768) {
        int j = idx - 16384; int n = j >> 7, k = j & 127;
        wt2[j] = f2bf(W2[k * HID + n]);
    } else if (idx < 38912) {
        int j = idx - 32768; int n = j >> 7, k = j & 127;
        wt3[j] = f2bf(W3[k * NF + n]);
    }
}

// pure block scan + one atomic/block -> exclusive offsets
__global__ void scan_kernel(const int* __restrict__ cnt, int* __restrict__ off,
                            int* __restrict__ counter) {
    __shared__ int sd[256];
    __shared__ int sbase;
    int tid = threadIdx.x;
    int n = blockIdx.x * 256 + tid;
    int v = (n < NN) ? cnt[n] : 0;
    sd[tid] = v;
    __syncthreads();
#pragma unroll
    for (int d = 1; d < 256; d <<= 1) {
        int t = (tid >= d) ? sd[tid - d] : 0;
        __syncthreads();
        sd[tid] += t;
        __syncthreads();
    }
    if (tid == 255) sbase = atomicAdd(counter, sd[255]);
    __syncthreads();
    if (n < NN) off[n] = sbase + sd[tid] - v;  // exclusive
}

__global__ void place_kernel(const int* __restrict__ ei, int* __restrict__ off,
                             unsigned long long* __restrict__ srt) {
    int e = blockIdx.x * 256 + threadIdx.x;  // NE exact
    int t = ei[NE + e];
    int p = atomicAdd(off + t, 1);  // off consumed (dead after this kernel)
    srt[p] = (unsigned long long)e | ((unsigned long long)ei[e] << 21) |
             ((unsigned long long)t << 38);
}

// swizzled LDS frag helper: row stride 256B, 16B granules, granule g stored at g^(row&15)
__device__ __forceinline__ const short8* frag_ptr(const unsigned short* base, int row, int s,
                                                  int lane15, int quad) {
    return (const short8*)((const char*)base + row * 256 + (((s * 4 + quad) ^ lane15) << 4));
}

// issue 14 float4 gather loads for half an edge row (sub = which half)
__device__ __forceinline__ void gather_issue(const float* __restrict__ x,
                                             const float* __restrict__ ef,
                                             unsigned long long pk, int sub, float4* v) {
    int eid = (int)(pk & 0x1FFFFFull);
    int src = (int)((pk >> 21) & 0x1FFFFull);
    int tgt = (int)(pk >> 38);
#pragma unroll
    for (int j = 0; j < 14; ++j) {
        int p = 2 * j + sub;
        const float4* gp;
        if (p < 12)      gp = (const float4*)(x + 48 * (size_t)src) + p;
        else if (p < 24) gp = (const float4*)(x + 48 * (size_t)tgt) + (p - 12);
        else             gp = (const float4*)(ef + 16 * (size_t)eid) + (p - 24);
        v[j] = *gp;
    }
}

__launch_bounds__(512, 2)
__global__ void gemm_kernel(const float* __restrict__ x, const float* __restrict__ ef,
                            const unsigned long long* __restrict__ srt,
                            const unsigned short* __restrict__ wt1,
                            const unsigned short* __restrict__ wt2,
                            const unsigned short* __restrict__ wt3,
                            const float* __restrict__ b1, const float* __restrict__ b2,
                            float* __restrict__ out_acc) {
    __shared__ __align__(16) unsigned short lw2[128 * 128];  // 32 KB
    __shared__ __align__(16) unsigned short lw3[48 * 128];   // 12 KB
    __shared__ __align__(16) unsigned short ea[TILE * 128];  // 64 KB: E -> h1 -> h2 -> msg
    __shared__ float lb1[128], lb2[128];
    __shared__ int wseg_start[8][33];  // per-wave run starts + sentinel
    __shared__ int wseg_tgt[8][32];

    const int tid = threadIdx.x;
    // ---- stage L2/L3 weights swizzled (once per persistent block); W1 streams from L2
    const uint4* s2 = (const uint4*)wt2;
    for (int i = tid; i < 2048; i += 512) {
        int n = i >> 4, g = i & 15;
        *(uint4*)((char*)lw2 + n * 256 + ((g ^ (n & 15)) << 4)) = s2[i];
    }
    const uint4* s3 = (const uint4*)wt3;
    for (int i = tid; i < 768; i += 512) {
        int n = i >> 4, g = i & 15;
        *(uint4*)((char*)lw3 + n * 256 + ((g ^ (n & 15)) << 4)) = s3[i];
    }
    if (tid < 128) lb1[tid] = b1[tid];
    else if (tid < 256) lb2[tid - 128] = b2[tid - 128];
    __syncthreads();  // weights read-only from here on; no further barriers needed

    const int l15 = tid & 15;
    const int q = (tid & 63) >> 4;
    const int ln = tid & 63;
    const int wave = tid >> 6;
    const int sub = ln & 1;                  // 2 lanes per edge row
    const int grow = wave * 32 + (ln >> 1);  // tile-local edge row (0..255)
    const int gl15 = grow & 15;
    const int G = gridDim.x;

    // per-thread constant base for streamed W1 frags: frag(mt,s) at +mt*2048 + s*32 shorts
    const unsigned short* w1base = wt1 + l15 * 128 + q * 8;

    // ---- pipeline prologue: srt 2 ahead, gather data 1 ahead (held in registers)
    unsigned long long pkCur = srt[(size_t)blockIdx.x * TILE + grow];
    unsigned long long pkNext = (blockIdx.x + G < NTILE)
        ? srt[(size_t)(blockIdx.x + G) * TILE + grow] : 0ull;
    float4 v[14];
    gather_issue(x, ef, pkCur, sub, v);

    for (int tile = blockIdx.x; tile < NTILE; tile += G) {
        // ============ PHASE: convert (consumes v; writes ea E rows; run enum) ========
        int nrun;
        {
            int tgt = (int)(pkCur >> 38);
            int tprev = __shfl(tgt, ln - 2);          // tgt of previous edge row
            int r = ln >> 1;                          // chunk-local row (0..31)
            int startf = (r == 0) || (tgt != tprev);
            unsigned long long mask = __ballot(startf && (sub == 0));
            nrun = __popcll(mask);
            if (startf && sub == 0) {
                int sid = __popcll(mask & ((1ull << ln) - 1ull));
                wseg_start[wave][sid] = r;
                wseg_tgt[wave][sid] = tgt;
            }
            if (ln == 0) wseg_start[wave][nrun] = 32;  // sentinel
#pragma unroll
            for (int j = 0; j < 14; ++j) {
                uint2 h = make_uint2(pk2(v[j].x, v[j].y), pk2(v[j].z, v[j].w));
                *(uint2*)((char*)ea + grow * 256 + ((j ^ gl15) << 4) + (sub << 3)) = h;
            }
            // zero-pad cols 112..127: granules 14,15 (one uint4 per lane)
            *(uint4*)((char*)ea + grow * 256 + (((14 + sub) ^ gl15) << 4)) =
                make_uint4(0u, 0u, 0u, 0u);
        }
        __builtin_amdgcn_sched_barrier(0);  // WALL: nothing from L1 hoists into convert

        // ============ PHASE: L1 with W1 streamed from global (VMEM pipe) =============
        // vmcnt queue is empty here (convert drained the gathers). 2-deep mt ping-pong
        // with inner fences: in-flight weight loads capped at 8.
        __builtin_amdgcn_s_setprio(1);
        {
            short8 bf[2][4];
#pragma unroll
            for (int gi = 0; gi < 2; ++gi)
#pragma unroll
                for (int s = 0; s < 4; ++s)
                    bf[gi][s] = *frag_ptr(ea, (wave * 2 + gi) * 16 + l15, s, l15, q);
            short8 w[2][4];
#pragma unroll
            for (int s = 0; s < 4; ++s)
                w[0][s] = *(const short8*)(w1base + s * 32);
#pragma unroll
            for (int mt = 0; mt < 8; ++mt) {
                if (mt < 7) {
#pragma unroll
                    for (int s = 0; s < 4; ++s)
                        w[(mt + 1) & 1][s] = *(const short8*)(w1base + (mt + 1) * 2048 + s * 32);
                }
                __builtin_amdgcn_sched_barrier(0);  // loads stay above; cap in-flight
                floatx4 a0 = (floatx4){0.f, 0.f, 0.f, 0.f};
                floatx4 a1 = (floatx4){0.f, 0.f, 0.f, 0.f};
#pragma unroll
                for (int s = 0; s < 4; ++s) {
                    a0 = __builtin_amdgcn_mfma_f32_16x16x32_bf16(w[mt & 1][s], bf[0][s], a0, 0, 0, 0);
                    a1 = __builtin_amdgcn_mfma_f32_16x16x32_bf16(w[mt & 1][s], bf[1][s], a1, 0, 0, 0);
                }
                int f0 = mt * 16 + q * 4;
                const float4 bv = *(const float4*)(lb1 + f0);
                uint2 h0 = make_uint2(pk2(fmaxf(a0[0] + bv.x, 0.f), fmaxf(a0[1] + bv.y, 0.f)),
                                      pk2(fmaxf(a0[2] + bv.z, 0.f), fmaxf(a0[3] + bv.w, 0.f)));
                uint2 h1 = make_uint2(pk2(fmaxf(a1[0] + bv.x, 0.f), fmaxf(a1[1] + bv.y, 0.f)),
                                      pk2(fmaxf(a1[2] + bv.z, 0.f), fmaxf(a1[3] + bv.w, 0.f)));
                int gran = 2 * mt + (q >> 1), off8 = (q & 1) << 3;
                *(uint2*)((char*)ea + (wave * 32 + l15) * 256 + ((gran ^ l15) << 4) + off8) = h0;
                *(uint2*)((char*)ea + (wave * 32 + 16 + l15) * 256 + ((gran ^ l15) << 4) + off8) = h1;
                __builtin_amdgcn_sched_barrier(0);  // next iter's loads can't hoist past
            }
        }
        __builtin_amdgcn_sched_barrier(0);  // WALL: gather issue can't hoist into L1

        // ============ PHASE: issue next-tile gather (flies over L2+L3+reduce) ========
        {
            unsigned long long pkN2 = 0ull;
            if (tile + 2 * G < NTILE)
                pkN2 = srt[(size_t)(tile + 2 * G) * TILE + grow];
            if (tile + G < NTILE)
                gather_issue(x, ef, pkNext, sub, v);
            pkCur = pkNext;
            pkNext = pkN2;
        }
        __builtin_amdgcn_sched_barrier(0);  // WALL: loads don't sink into L2/L3

        // ============ PHASE: L2 from LDS weights, in-place ===========================
        {
            short8 bf[2][4];
#pragma unroll
            for (int gi = 0; gi < 2; ++gi)
#pragma unroll
                for (int s = 0; s < 4; ++s)
                    bf[gi][s] = *frag_ptr(ea, (wave * 2 + gi) * 16 + l15, s, l15, q);
#pragma unroll
            for (int mt = 0; mt < 8; ++mt) {
                floatx4 a0 = (floatx4){0.f, 0.f, 0.f, 0.f};
                floatx4 a1 = (floatx4){0.f, 0.f, 0.f, 0.f};
#pragma unroll
                for (int s = 0; s < 4; ++s) {
                    short8 a = *frag_ptr(lw2, mt * 16 + l15, s, l15, q);
                    a0 = __builtin_amdgcn_mfma_f32_16x16x32_bf16(a, bf[0][s], a0, 0, 0, 0);
                    a1 = __builtin_amdgcn_mfma_f32_16x16x32_bf16(a, bf[1][s], a1, 0, 0, 0);
                }
                int f0 = mt * 16 + q * 4;
                const float4 bv = *(const float4*)(lb2 + f0);
                uint2 h0 = make_uint2(pk2(fmaxf(a0[0] + bv.x, 0.f), fmaxf(a0[1] + bv.y, 0.f)),
                                      pk2(fmaxf(a0[2] + bv.z, 0.f), fmaxf(a0[3] + bv.w, 0.f)));
                uint2 h1 = make_uint2(pk2(fmaxf(a1[0] + bv.x, 0.f), fmaxf(a1[1] + bv.y, 0.f)),
                                      pk2(fmaxf(a1[2] + bv.z, 0.f), fmaxf(a1[3] + bv.w, 0.f)));
                int gran = 2 * mt + (q >> 1), off8 = (q & 1) << 3;
                *(uint2*)((char*)ea + (wave * 32 + l15) * 256 + ((gran ^ l15) << 4) + off8) = h0;
                *(uint2*)((char*)ea + (wave * 32 + 16 + l15) * 256 + ((gran ^ l15) << 4) + off8) = h1;
            }
        }
        // ============ PHASE: L3 from LDS weights, msg fp32 in-place ==================
        {
            short8 bf[2][4];
#pragma unroll
            for (int gi = 0; gi < 2; ++gi)
#pragma unroll
                for (int s = 0; s < 4; ++s)
                    bf[gi][s] = *frag_ptr(ea, (wave * 2 + gi) * 16 + l15, s, l15, q);
#pragma unroll
            for (int mt = 0; mt < 3; ++mt) {
                floatx4 a0 = (floatx4){0.f, 0.f, 0.f, 0.f};
                floatx4 a1 = (floatx4){0.f, 0.f, 0.f, 0.f};
#pragma unroll
                for (int s = 0; s < 4; ++s) {
                    short8 a = *frag_ptr(lw3, mt * 16 + l15, s, l15, q);
                    a0 = __builtin_amdgcn_mfma_f32_16x16x32_bf16(a, bf[0][s], a0, 0, 0, 0);
                    a1 = __builtin_amdgcn_mfma_f32_16x16x32_bf16(a, bf[1][s], a1, 0, 0, 0);
                }
                int gran = mt * 4 + q;  // fp32 granule, full 16B
                *(float4*)((char*)ea + (wave * 32 + l15) * 256 + ((gran ^ l15) << 4)) =
                    *(float4*)&a0;
                *(float4*)((char*)ea + (wave * 32 + 16 + l15) * 256 + ((gran ^ l15) << 4)) =
                    *(float4*)&a1;
            }
        }
        __builtin_amdgcn_s_setprio(0);
        __builtin_amdgcn_sched_barrier(0);  // WALL: reduce stays below L3

        // ============ PHASE: per-wave segment reduce over OWN 32 rows ================
        //      (no barrier: same-wave DS ordering covers msg writes above and wseg
        //      writes at convert). Boundary runs (k==0 / k==nrun-1) may continue in
        //      neighboring chunks/blocks -> atomicAdd; interior runs are globally
        //      exclusive (sorted srt) -> plain store. out_acc is zero-initialized.
        if (ln < 48) {
            const int gcol = ln >> 2, coff = (ln & 3) << 2;
            const char* wbase = (const char*)ea + wave * 32 * 256;  // wave*32 % 16 == 0
            for (int k = 0; k < nrun; ++k) {
                int a = wseg_start[wave][k], bnd = wseg_start[wave][k + 1];
                float s0 = 0.f, s1f = 0.f;
                int p = a;
                for (; p + 1 < bnd; p += 2) {
                    s0  += *(const float*)(wbase + p * 256 + ((gcol ^ (p & 15)) << 4) + coff);
                    s1f += *(const float*)(wbase + (p + 1) * 256 +
                                           ((gcol ^ ((p + 1) & 15)) << 4) + coff);
                }
                if (p < bnd)
                    s0 += *(const float*)(wbase + p * 256 + ((gcol ^ (p & 15)) << 4) + coff);
                float sum = s0 + s1f;
                float* dst = out_acc + 48 * (size_t)wseg_tgt[wave][k] + ln;
                if (k == 0 || k == nrun - 1) atomicAdd(dst, sum);  // may span chunk edge
                else *dst = sum;                                   // exclusive run
            }
        }
        // no barrier: each wave proceeds to its next tile independently
    }
}

__global__ void finalize_kernel(const float* __restrict__ x, const int* __restrict__ cnt,
                                const float* __restrict__ b3, float* __restrict__ out) {
    int i = blockIdx.x * 256 + threadIdx.x;  // over NN*12 float4s
    if (i >= NN * 12) return;
    int node = i / 12, j = i % 12;
    float c = (float)cnt[node];
    float4 xv = ((const float4*)x)[i];
    float4 ov = ((const float4*)out)[i];
    float4 bv = ((const float4*)b3)[j];
    float4 r;
    if (c > 0.f) {
        float rc = 1.f / c;
        r.x = xv.x + ov.x * rc + bv.x;
        r.y = xv.y + ov.y * rc + bv.y;
        r.z = xv.z + ov.z * rc + bv.z;
        r.w = xv.w + ov.w * rc + bv.w;
    } else {
        r = xv;
    }
    ((float4*)out)[i] = r;
}

extern "C" void kernel_launch(void* const* d_in, const int* in_sizes, int n_in,
                              void* d_out, int out_size, void* d_ws, size_t ws_size,
                              hipStream_t stream) {
    const float* x  = (const float*)d_in[0];
    const int*   ei = (const int*)d_in[1];
    const float* ef = (const float*)d_in[2];
    const float* W1 = (const float*)d_in[3];
    const float* b1 = (const float*)d_in[4];
    const float* W2 = (const float*)d_in[5];
    const float* b2 = (const float*)d_in[6];
    const float* W3 = (const float*)d_in[7];
    const float* b3 = (const float*)d_in[8];
    float* out = (float*)d_out;

    char* ws = (char*)d_ws;
    int* cnt     = (int*)ws;                    // 400000 B
    int* counter = (int*)(ws + 400000);         // 4 B (zeroed together with cnt)
    int* off     = (int*)(ws + 409600);         // 400000 B
    unsigned short* wt1 = (unsigned short*)(ws + 819456);
    unsigned short* wt2 = wt1 + 16384;
    unsigned short* wt3 = wt2 + 16384;          // ends ~897 KB
    unsigned long long* srt = (unsigned long long*)(ws + 901120);  // 12.8 MB

    hipMemsetAsync(out, 0, (size_t)out_size * sizeof(float), stream);
    hipMemsetAsync(cnt, 0, (size_t)NN * sizeof(int) + 4, stream);
    hist_prep_kernel<<<NTILE + 152, 256, 0, stream>>>(ei, cnt, W1, W2, W3, wt1, wt2, wt3);
    scan_kernel<<<391, 256, 0, stream>>>(cnt, off, counter);
    place_kernel<<<6250, 256, 0, stream>>>(ei, off, srt);
    gemm_kernel<<<256, 512, 0, stream>>>(x, ef, srt, wt1, wt2, wt3, b1, b2, out);
    finalize_kernel<<<4688, 256, 0, stream>>>(x, cnt, b3, out);
}

// Round 11
// 531.772 us; speedup vs baseline: 2.7950x; 1.3607x over previous
//
#include <hip/hip_runtime.h>
#include <hip/hip_bf16.h>

// GNN message passing: gather(x[src],x[tgt],ef) -> MLP(112->128->128->48) -> scatter-mean.
// R19 = R18 with the out-zero sizing bug fixed (ZBLK 1172->4688: out is NN*NF=4.8M
// floats = 1.2M float4, not 300k; R18 would have left 75% of the accumulator dirty).
// R18's bench died on container infra, never ran.
// Streaming post-mortem (R12/R13/R15/R16/R17): every weight-streaming variant spilled
// with the same signature (VGPR pinned 128 = the HW 4-wave/SIMD budget, FETCH +260MB
// scratch) across three containment mechanisms (launch-bounds, inner fences, full
// phase walls). Conclusion: R11's 100-VGPR structure is the gemm plateau. STOP.
// This round targets the aux pipeline (e2e = gemm 187us + aux ~335us):
//  - hist: 4 edges/thread via int4 (coalesced, 6250->1563 blocks; atomics unchanged)
//  - place: 4 edges/thread via 2x int4
//  - out-zeroing folded into hist_prep (one fewer dispatch; gemm launches after)
// gemm unchanged from R11: lw1/lw2/lw3 in LDS, barrier-free tile loop, per-wave run
// enum + wave-private reduce (boundary atomicAdd, interior plain store), cross-tile
// gather prefetch (srt 2 ahead, v[14] 1 ahead), setprio around MFMA.
// Revert check: gemm dispatch must show dur~187, VGPR 100, FETCH ~285MB, LDS 146944.

#define NN 100000
#define NE 1600000
#define NF 48
#define TOT 112
#define HID 128
#define TILE 256
#define NTILE 6250   // NE/256 (gemm tiles)
#define NQUAD 400000 // NE/4 (hist/place quads)
#define HBLK 1563    // ceil(NQUAD/256)
#define WBLK 152     // weight-prep blocks (38912/256)
#define ZBLK 4688    // out-zero blocks: NN*NF/4 = 1.2M float4 / 256 = 4687.5 -> 4688

typedef __attribute__((ext_vector_type(8))) short short8;
typedef __attribute__((ext_vector_type(4))) float floatx4;

__device__ __forceinline__ unsigned short f2bf(float f) {
    union { float f; unsigned u; } v; v.f = f;
    unsigned u = v.u;
    return (unsigned short)((u + 0x7FFFu + ((u >> 16) & 1u)) >> 16);  // RNE
}
__device__ __forceinline__ unsigned pk2(float a, float b) {
    __hip_bfloat162 h = __float22bfloat162_rn(make_float2(a, b));
    return *(unsigned*)&h;  // low16 = a, high16 = b
}

// ---- hist (x4 vectorized) + prep W->WT bf16 + out zeroing, one dispatch
__global__ void hist_prep_kernel(const int* __restrict__ ei, int* __restrict__ cnt,
                                 const float* __restrict__ W1, const float* __restrict__ W2,
                                 const float* __restrict__ W3,
                                 unsigned short* __restrict__ wt1,
                                 unsigned short* __restrict__ wt2,
                                 unsigned short* __restrict__ wt3,
                                 float4* __restrict__ out4, int nout4) {
    if (blockIdx.x < HBLK) {
        int qd = blockIdx.x * 256 + threadIdx.x;
        if (qd < NQUAD) {
            int4 t4 = *(const int4*)(ei + NE + 4 * qd);  // 4 targets, 16B coalesced
            atomicAdd(cnt + t4.x, 1);
            atomicAdd(cnt + t4.y, 1);
            atomicAdd(cnt + t4.z, 1);
            atomicAdd(cnt + t4.w, 1);
        }
        return;
    }
    if (blockIdx.x < HBLK + WBLK) {
        int idx = (blockIdx.x - HBLK) * 256 + threadIdx.x;
        if (idx < 16384) {
            int n = idx >> 7, k = idx & 127;
            wt1[idx] = (k < TOT) ? f2bf(W1[k * HID + n]) : (unsigned short)0;
        } else if (idx < 32768) {
            int j = idx - 16384; int n = j >> 7, k = j & 127;
            wt2[j] = f2bf(W2[k * HID + n]);
        } else if (idx < 38912) {
            int j = idx - 32768; int n = j >> 7, k = j & 127;
            wt3[j] = f2bf(W3[k * NF + n]);
        }
        return;
    }
    int z = (blockIdx.x - HBLK - WBLK) * 256 + threadIdx.x;
    if (z < nout4) out4[z] = make_float4(0.f, 0.f, 0.f, 0.f);
}

// pure block scan + one atomic/block -> exclusive offsets
__global__ void scan_kernel(const int* __restrict__ cnt, int* __restrict__ off,
                            int* __restrict__ counter) {
    __shared__ int sd[256];
    __shared__ int sbase;
    int tid = threadIdx.x;
    int n = blockIdx.x * 256 + tid;
    int v = (n < NN) ? cnt[n] : 0;
    sd[tid] = v;
    __syncthreads();
#pragma unroll
    for (int d = 1; d < 256; d <<= 1) {
        int t = (tid >= d) ? sd[tid - d] : 0;
        __syncthreads();
        sd[tid] += t;
        __syncthreads();
    }
    if (tid == 255) sbase = atomicAdd(counter, sd[255]);
    __syncthreads();
    if (n < NN) off[n] = sbase + sd[tid] - v;  // exclusive
}

// x4 vectorized: 4 edges/thread, two int4 loads, 4 atomics, 4 scattered u64 writes
__global__ void place_kernel(const int* __restrict__ ei, int* __restrict__ off,
                             unsigned long long* __restrict__ srt) {
    int qd = blockIdx.x * 256 + threadIdx.x;
    if (qd >= NQUAD) return;
    int e = 4 * qd;
    int4 s4 = *(const int4*)(ei + e);       // sources
    int4 t4 = *(const int4*)(ei + NE + e);  // targets
#pragma unroll
    for (int j = 0; j < 4; ++j) {
        int s = (j == 0) ? s4.x : (j == 1) ? s4.y : (j == 2) ? s4.z : s4.w;
        int t = (j == 0) ? t4.x : (j == 1) ? t4.y : (j == 2) ? t4.z : t4.w;
        int p = atomicAdd(off + t, 1);
        srt[p] = (unsigned long long)(e + j) | ((unsigned long long)s << 21) |
                 ((unsigned long long)t << 38);
    }
}

// swizzled LDS frag helper: row stride 256B, 16B granules, granule g stored at g^(row&15)
__device__ __forceinline__ const short8* frag_ptr(const unsigned short* base, int row, int s,
                                                  int lane15, int quad) {
    return (const short8*)((const char*)base + row * 256 + (((s * 4 + quad) ^ lane15) << 4));
}

// issue 14 float4 gather loads for half an edge row (sub = which half)
__device__ __forceinline__ void gather_issue(const float* __restrict__ x,
                                             const float* __restrict__ ef,
                                             unsigned long long pk, int sub, float4* v) {
    int eid = (int)(pk & 0x1FFFFFull);
    int src = (int)((pk >> 21) & 0x1FFFFull);
    int tgt = (int)(pk >> 38);
#pragma unroll
    for (int j = 0; j < 14; ++j) {
        int p = 2 * j + sub;
        const float4* gp;
        if (p < 12)      gp = (const float4*)(x + 48 * (size_t)src) + p;
        else if (p < 24) gp = (const float4*)(x + 48 * (size_t)tgt) + (p - 12);
        else             gp = (const float4*)(ef + 16 * (size_t)eid) + (p - 24);
        v[j] = *gp;
    }
}

__launch_bounds__(512, 2)
__global__ void gemm_kernel(const float* __restrict__ x, const float* __restrict__ ef,
                            const unsigned long long* __restrict__ srt,
                            const unsigned short* __restrict__ wt1,
                            const unsigned short* __restrict__ wt2,
                            const unsigned short* __restrict__ wt3,
                            const float* __restrict__ b1, const float* __restrict__ b2,
                            float* __restrict__ out_acc) {
    __shared__ __align__(16) unsigned short lw1[128 * 128];  // 32 KB
    __shared__ __align__(16) unsigned short lw2[128 * 128];  // 32 KB
    __shared__ __align__(16) unsigned short lw3[48 * 128];   // 12 KB
    __shared__ __align__(16) unsigned short ea[TILE * 128];  // 64 KB: E -> h1 -> h2 -> msg
    __shared__ float lb1[128], lb2[128];
    __shared__ int wseg_start[8][33];  // per-wave run starts + sentinel
    __shared__ int wseg_tgt[8][32];

    const int tid = threadIdx.x;
    // ---- stage weights swizzled (once per persistent block)
    const uint4* s1 = (const uint4*)wt1;
    for (int i = tid; i < 2048; i += 512) {
        int n = i >> 4, g = i & 15;
        *(uint4*)((char*)lw1 + n * 256 + ((g ^ (n & 15)) << 4)) = s1[i];
    }
    const uint4* s2 = (const uint4*)wt2;
    for (int i = tid; i < 2048; i += 512) {
        int n = i >> 4, g = i & 15;
        *(uint4*)((char*)lw2 + n * 256 + ((g ^ (n & 15)) << 4)) = s2[i];
    }
    const uint4* s3 = (const uint4*)wt3;
    for (int i = tid; i < 768; i += 512) {
        int n = i >> 4, g = i & 15;
        *(uint4*)((char*)lw3 + n * 256 + ((g ^ (n & 15)) << 4)) = s3[i];
    }
    if (tid < 128) lb1[tid] = b1[tid];
    else if (tid < 256) lb2[tid - 128] = b2[tid - 128];
    __syncthreads();  // weights read-only from here on; no further barriers needed

    const int l15 = tid & 15;
    const int q = (tid & 63) >> 4;
    const int ln = tid & 63;
    const int wave = tid >> 6;
    const int sub = ln & 1;                  // 2 lanes per edge row
    const int grow = wave * 32 + (ln >> 1);  // tile-local edge row (0..255)
    const int gl15 = grow & 15;
    const int G = gridDim.x;

    // ---- pipeline prologue: srt 2 ahead, gather data 1 ahead (held in registers)
    unsigned long long pkCur = srt[(size_t)blockIdx.x * TILE + grow];
    unsigned long long pkNext = (blockIdx.x + G < NTILE)
        ? srt[(size_t)(blockIdx.x + G) * TILE + grow] : 0ull;
    float4 v[14];
    gather_issue(x, ef, pkCur, sub, v);

    for (int tile = blockIdx.x; tile < NTILE; tile += G) {
        // ---- consume prefetched gather: convert + swizzled store into ea (own rows
        //      only) + per-wave run enumeration (no cross-wave data anywhere)
        int nrun;
        {
            int tgt = (int)(pkCur >> 38);
            int tprev = __shfl(tgt, ln - 2);          // tgt of previous edge row
            int r = ln >> 1;                          // chunk-local row (0..31)
            int startf = (r == 0) || (tgt != tprev);
            unsigned long long mask = __ballot(startf && (sub == 0));
            nrun = __popcll(mask);
            if (startf && sub == 0) {
                int sid = __popcll(mask & ((1ull << ln) - 1ull));
                wseg_start[wave][sid] = r;
                wseg_tgt[wave][sid] = tgt;
            }
            if (ln == 0) wseg_start[wave][nrun] = 32;  // sentinel
#pragma unroll
            for (int j = 0; j < 14; ++j) {
                uint2 h = make_uint2(pk2(v[j].x, v[j].y), pk2(v[j].z, v[j].w));
                *(uint2*)((char*)ea + grow * 256 + ((j ^ gl15) << 4) + (sub << 3)) = h;
            }
            // zero-pad cols 112..127: granules 14,15 (one uint4 per lane)
            *(uint4*)((char*)ea + grow * 256 + (((14 + sub) ^ gl15) << 4)) =
                make_uint4(0u, 0u, 0u, 0u);
        }
        // ---- issue next-tile prefetch NOW; it flies under MFMA + reduce below
        {
            unsigned long long pkN2 = 0ull;
            if (tile + 2 * G < NTILE)
                pkN2 = srt[(size_t)(tile + 2 * G) * TILE + grow];
            if (tile + G < NTILE)
                gather_issue(x, ef, pkNext, sub, v);
            pkCur = pkNext;
            pkNext = pkN2;
        }
        __builtin_amdgcn_sched_barrier(0);  // don't let the scheduler sink the loads

        __builtin_amdgcn_s_setprio(1);
        // ---- L1, L2 in-place (frags registered before stores; same-wave DS in order)
#pragma unroll
        for (int layer = 0; layer < 2; ++layer) {
            const unsigned short* lw = layer ? lw2 : lw1;
            const float* lb = layer ? lb2 : lb1;
            short8 bf[2][4];
#pragma unroll
            for (int gi = 0; gi < 2; ++gi)
#pragma unroll
                for (int s = 0; s < 4; ++s)
                    bf[gi][s] = *frag_ptr(ea, (wave * 2 + gi) * 16 + l15, s, l15, q);
#pragma unroll
            for (int mt = 0; mt < 8; ++mt) {
                floatx4 a0 = (floatx4){0.f, 0.f, 0.f, 0.f};
                floatx4 a1 = (floatx4){0.f, 0.f, 0.f, 0.f};
#pragma unroll
                for (int s = 0; s < 4; ++s) {
                    short8 a = *frag_ptr(lw, mt * 16 + l15, s, l15, q);
                    a0 = __builtin_amdgcn_mfma_f32_16x16x32_bf16(a, bf[0][s], a0, 0, 0, 0);
                    a1 = __builtin_amdgcn_mfma_f32_16x16x32_bf16(a, bf[1][s], a1, 0, 0, 0);
                }
                int f0 = mt * 16 + q * 4;
                const float4 bv = *(const float4*)(lb + f0);
                uint2 h0 = make_uint2(pk2(fmaxf(a0[0] + bv.x, 0.f), fmaxf(a0[1] + bv.y, 0.f)),
                                      pk2(fmaxf(a0[2] + bv.z, 0.f), fmaxf(a0[3] + bv.w, 0.f)));
                uint2 h1 = make_uint2(pk2(fmaxf(a1[0] + bv.x, 0.f), fmaxf(a1[1] + bv.y, 0.f)),
                                      pk2(fmaxf(a1[2] + bv.z, 0.f), fmaxf(a1[3] + bv.w, 0.f)));
                int gran = 2 * mt + (q >> 1), off8 = (q & 1) << 3;
                *(uint2*)((char*)ea + (wave * 32 + l15) * 256 + ((gran ^ l15) << 4) + off8) = h0;
                *(uint2*)((char*)ea + (wave * 32 + 16 + l15) * 256 + ((gran ^ l15) << 4) + off8) = h1;
            }
        }
        // ---- L3: msg fp32 in-place (h2 dead after frag reads)
        {
            short8 bf[2][4];
#pragma unroll
            for (int gi = 0; gi < 2; ++gi)
#pragma unroll
                for (int s = 0; s < 4; ++s)
                    bf[gi][s] = *frag_ptr(ea, (wave * 2 + gi) * 16 + l15, s, l15, q);
#pragma unroll
            for (int mt = 0; mt < 3; ++mt) {
                floatx4 a0 = (floatx4){0.f, 0.f, 0.f, 0.f};
                floatx4 a1 = (floatx4){0.f, 0.f, 0.f, 0.f};
#pragma unroll
                for (int s = 0; s < 4; ++s) {
                    short8 a = *frag_ptr(lw3, mt * 16 + l15, s, l15, q);
                    a0 = __builtin_amdgcn_mfma_f32_16x16x32_bf16(a, bf[0][s], a0, 0, 0, 0);
                    a1 = __builtin_amdgcn_mfma_f32_16x16x32_bf16(a, bf[1][s], a1, 0, 0, 0);
                }
                int gran = mt * 4 + q;  // fp32 granule, full 16B
                *(float4*)((char*)ea + (wave * 32 + l15) * 256 + ((gran ^ l15) << 4)) =
                    *(float4*)&a0;
                *(float4*)((char*)ea + (wave * 32 + 16 + l15) * 256 + ((gran ^ l15) << 4)) =
                    *(float4*)&a1;
            }
        }
        __builtin_amdgcn_s_setprio(0);
        // ---- per-wave segment reduce over OWN 32 rows (no barrier: same-wave DS
        //      ordering covers msg writes above and wseg writes at convert).
        //      Boundary runs (k==0 / k==nrun-1) may continue in neighboring chunks or
        //      blocks -> atomicAdd; interior runs are globally exclusive (sorted srt)
        //      -> plain store. out_acc is zero-initialized.
        if (ln < 48) {
            const int gcol = ln >> 2, coff = (ln & 3) << 2;
            const char* wbase = (const char*)ea + wave * 32 * 256;  // wave*32 % 16 == 0
            for (int k = 0; k < nrun; ++k) {
                int a = wseg_start[wave][k], bnd = wseg_start[wave][k + 1];
                float s0 = 0.f, s1f = 0.f;
                int p = a;
                for (; p + 1 < bnd; p += 2) {
                    s0  += *(const float*)(wbase + p * 256 + ((gcol ^ (p & 15)) << 4) + coff);
                    s1f += *(const float*)(wbase + (p + 1) * 256 +
                                           ((gcol ^ ((p + 1) & 15)) << 4) + coff);
                }
                if (p < bnd)
                    s0 += *(const float*)(wbase + p * 256 + ((gcol ^ (p & 15)) << 4) + coff);
                float sum = s0 + s1f;
                float* dst = out_acc + 48 * (size_t)wseg_tgt[wave][k] + ln;
                if (k == 0 || k == nrun - 1) atomicAdd(dst, sum);  // may span chunk edge
                else *dst = sum;                                   // exclusive run
            }
        }
        // no barrier: each wave proceeds to its next tile independently
    }
}

__global__ void finalize_kernel(const float* __restrict__ x, const int* __restrict__ cnt,
                                const float* __restrict__ b3, float* __restrict__ out) {
    int i = blockIdx.x * 256 + threadIdx.x;  // over NN*12 float4s
    if (i >= NN * 12) return;
    int node = i / 12, j = i % 12;
    float c = (float)cnt[node];
    float4 xv = ((const float4*)x)[i];
    float4 ov = ((const float4*)out)[i];
    float4 bv = ((const float4*)b3)[j];
    float4 r;
    if (c > 0.f) {
        float rc = 1.f / c;
        r.x = xv.x + ov.x * rc + bv.x;
        r.y = xv.y + ov.y * rc + bv.y;
        r.z = xv.z + ov.z * rc + bv.z;
        r.w = xv.w + ov.w * rc + bv.w;
    } else {
        r = xv;
    }
    ((float4*)out)[i] = r;
}

extern "C" void kernel_launch(void* const* d_in, const int* in_sizes, int n_in,
                              void* d_out, int out_size, void* d_ws, size_t ws_size,
                              hipStream_t stream) {
    const float* x  = (const float*)d_in[0];
    const int*   ei = (const int*)d_in[1];
    const float* ef = (const float*)d_in[2];
    const float* W1 = (const float*)d_in[3];
    const float* b1 = (const float*)d_in[4];
    const float* W2 = (const float*)d_in[5];
    const float* b2 = (const float*)d_in[6];
    const float* W3 = (const float*)d_in[7];
    const float* b3 = (const float*)d_in[8];
    float* out = (float*)d_out;

    char* ws = (char*)d_ws;
    int* cnt     = (int*)ws;                    // 400000 B
    int* counter = (int*)(ws + 400000);         // 4 B (zeroed together with cnt)
    int* off     = (int*)(ws + 409600);         // 400000 B
    unsigned short* wt1 = (unsigned short*)(ws + 819456);
    unsigned short* wt2 = wt1 + 16384;
    unsigned short* wt3 = wt2 + 16384;          // ends ~897 KB
    unsigned long long* srt = (unsigned long long*)(ws + 901120);  // 12.8 MB

    hipMemsetAsync(cnt, 0, (size_t)NN * sizeof(int) + 4, stream);
    int nout4 = out_size / 4;  // out_size floats -> float4 count (4.8M -> 1.2M)
    hist_prep_kernel<<<HBLK + WBLK + ZBLK, 256, 0, stream>>>(
        ei, cnt, W1, W2, W3, wt1, wt2, wt3, (float4*)out, nout4);
    scan_kernel<<<391, 256, 0, stream>>>(cnt, off, counter);
    place_kernel<<<HBLK, 256, 0, stream>>>(ei, off, srt);
    gemm_kernel<<<256, 512, 0, stream>>>(x, ef, srt, wt1, wt2, wt3, b1, b2, out);
    finalize_kernel<<<4688, 256, 0, stream>>>(x, cnt, b3, out);
}